// Round 20
// baseline (178.532 us; speedup 1.0000x reference)
//
#include <hip/hip_runtime.h>

// Problem constants (B=4, S=2048, D=1024, H=16, HD=64, theta=10000)
#define SB 2048
#define DM 1024
#define NH 16
#define HDim 64
#define NB 4
#define MROWS (NB*SB)   // 8192

typedef _Float16 h16;
typedef __attribute__((ext_vector_type(8))) _Float16 h16x8;
typedef __attribute__((ext_vector_type(4))) _Float16 h16x4;
typedef __attribute__((ext_vector_type(2))) _Float16 h16x2;
typedef __attribute__((ext_vector_type(2))) __fp16 fp16x2;
typedef __attribute__((ext_vector_type(4))) float f32x4;

typedef const __attribute__((address_space(1))) void* as1cp;
typedef __attribute__((address_space(3))) void* as3p;

__device__ __forceinline__ void gload16(const void* g, void* l){
  __builtin_amdgcn_global_load_lds((as1cp)g, (as3p)l, 16, 0, 0);
}
__device__ __forceinline__ int swz128(int a){ return a ^ (((a>>7)&7)<<4); }
// V k-permutation (pos->k) inverse, used when writing VT (see round-1 notes)
__device__ __forceinline__ int invp3(int k){ return (k&32) | ((k&16)>>2) | ((k&12)<<1) | (k&3); }
__device__ __forceinline__ h16x2 pkrtz(float a, float b){
  fp16x2 r = __builtin_amdgcn_cvt_pkrtz(a,b);
  return __builtin_bit_cast(h16x2, r);
}

#define C1 0.18033688f   // 0.125 * log2(e); folded into wq at cvt_w

// ------- merged prep: [0,2048) cvt_x | [2048,6144) cvt_w(+C1 on wq) | [6144,6400) RoPE tab -------
__global__ void k_prep(const float* __restrict__ x, h16* __restrict__ xb,
                       const float* __restrict__ wq, const float* __restrict__ wk,
                       const float* __restrict__ wv, const float* __restrict__ wo,
                       h16* __restrict__ WT,
                       const int* __restrict__ tok, float2* __restrict__ tab){
  __shared__ h16 tile[32][33];
  const int blk = blockIdx.x;
  if (blk < 2048){
    const int n4 = MROWS*DM/4;
    for (int i = blk*blockDim.x + threadIdx.x; i < n4; i += 2048*blockDim.x){
      float4 v = ((const float4*)x)[i];
      h16x4 h; h[0]=(h16)v.x; h[1]=(h16)v.y; h[2]=(h16)v.z; h[3]=(h16)v.w;
      ((h16x4*)xb)[i] = h;
    }
  } else if (blk < 6144){
    const int local = blk - 2048;
    const int z = local >> 10, rem = local & 1023;
    const float* W = (z==0)?wq:(z==1)?wk:(z==2)?wv:wo;
    const float sc = (z==0) ? C1 : 1.0f;
    int tx = threadIdx.x & 31, ty = threadIdx.x >> 5;
    int n0 = (rem & 31)*32, k0 = (rem >> 5)*32;
    #pragma unroll
    for (int j=0;j<4;++j)
      tile[ty*4+j][tx] = (h16)(W[(size_t)(k0+ty*4+j)*DM + n0 + tx] * sc);
    __syncthreads();
    #pragma unroll
    for (int j=0;j<4;++j)
      WT[((size_t)z*DM + n0 + ty*4 + j)*DM + k0 + tx] = tile[tx][ty*4+j];
  } else {
    int i = (blk - 6144)*blockDim.x + threadIdx.x;   // 65536 entries
    int pr = i & 31, s = i >> 5;
    float inv = exp2f(-0.41524101f * (float)pr);
    float ang = (float)tok[s] * inv;
    float sn, cs; __sincosf(ang, &sn, &cs);
    tab[i] = make_float2(cs, sn);
  }
}

// ======== 8-phase MFMA GEMM for QKV (MODE0 work), 256x256 tile, 8 waves ========
// Wave w owns 256 rows x 32 cols (cols 32w). Per K-tile (BK=64): 4 phases; phase q:
//   12 ds_read_b128 (A-chunk q [64 rows] + wave's B-half slice) || gload issues ->
//   s_barrier -> lgkmcnt(0) -> setprio(1) -> 16 MFMA -> setprio(0) -> s_barrier.
// LDS 128KB: A = 2buf x 4chunk x 8KB (offset 0); B = 2buf x 2half x 16KB (offset 64K).
// Issue schedule (counted-vmcnt, ONE wait/tile, never 0 until tail):
//   tile kt: ph0 -> B0(kt+1)[2] + A3(kt+1)[1]; ph1 -> B1(kt+1)[2];
//            ph2 -> A0(kt+2)[1] + A1(kt+2)[1]; ph3 -> A2(kt+2)[1];
//   end-of-tile vmcnt(3) leaves {A0,A1,A2(kt+2)} in flight ACROSS the barrier.
// WAR: intra-buffer overwrites (ph2/ph3 -> slots A0/A1/A2 of same buf) target slots
// whose block-wide reads retired >=1 phase earlier (phase barriers + lgkmcnt(0)).
__global__ __launch_bounds__(512, 2) void k_gemm8(const h16* __restrict__ A,
                                                  const h16* __restrict__ Bw,
                                                  h16* __restrict__ outp,
                                                  const float2* __restrict__ tab){
  __shared__ __align__(16) char lds[131072];
  const int t = threadIdx.x, lane = t & 63, wave = t >> 6;
  const int g = lane >> 4, l15 = lane & 15;
  const int wc = wave;                         // 8 n-slices of 32 cols
  // XCD block map: x owns 4 m-panels, m-fastest (grid 384 = 8 x 48)
  const int lin = blockIdx.x;
  const int x = lin & 7, local = lin >> 3;
  const int m0 = (x*4 + (local & 3))*256, n0 = (local >> 2)*256;
  // lane-constant LDS read bases (swz128 on 128B rows; ks via ^64)
  const int msk = (l15 & 7) << 4;
  int kbA[4], kbB[2];
  #pragma unroll
  for (int f=0; f<4; ++f) kbA[f] = ((((f<<4)+l15)<<7) + (g<<4)) ^ msk;
  #pragma unroll
  for (int fb=0; fb<2; ++fb) kbB[fb] = (((32*(wc&3) + (fb<<4) + l15)<<7) + (g<<4)) ^ msk;
  const int bhalf = (wc >> 2)*16384;
  // staging sources (pre-swizzled): A 1 load/chunk, B 2 loads/half
  const int oA = t*16;
  const int loA = swz128(oA);
  const char* Asrc = (const char*)A + (size_t)(m0 + (loA>>7))*2048 + (loA&127);
  const char* Bsrc[2]; int oB[2];
  #pragma unroll
  for (int i=0;i<2;++i){
    int o = t*16 + i*8192; oB[i] = o;
    int lo = swz128(o);
    Bsrc[i] = (const char*)Bw + (size_t)(n0 + (lo>>7))*2048 + (lo&127);
  }
  auto IA = [&](int T, int c){
    gload16(Asrc + (size_t)c*131072 + (size_t)T*128,
            lds + (T&1)*32768 + c*8192 + oA);
  };
  auto IB = [&](int T, int h){
    char* d = lds + 65536 + (T&1)*32768 + h*16384;
    const size_t so = (size_t)h*262144 + (size_t)T*128;
    gload16(Bsrc[0] + so, d + oB[0]);
    gload16(Bsrc[1] + so, d + oB[1]);
  };
  f32x4 acc[16][2] = {};
  // prologue: tile0 all 8 loads, then tile1 {A0,A1,A2} (last 3 survive vmcnt(3))
  IB(0,0); IB(0,1); IA(0,3); IA(0,0); IA(0,1); IA(0,2);
  IA(1,0); IA(1,1); IA(1,2);
  asm volatile("s_waitcnt vmcnt(3)" ::: "memory");
  __builtin_amdgcn_s_barrier();
  for (int kt=0; kt<16; ++kt){
    const int buf = kt & 1;
    const char* Ab = lds + buf*32768;
    const char* Bb = lds + 65536 + buf*32768 + bhalf;
    #pragma unroll
    for (int q=0; q<4; ++q){
      h16x8 af[4][2], bf[2][2];
      #pragma unroll
      for (int f=0; f<4; ++f){
        af[f][0] = *(const h16x8*)(Ab + q*8192 + kbA[f]);
        af[f][1] = *(const h16x8*)(Ab + q*8192 + (kbA[f]^64));
      }
      #pragma unroll
      for (int fb=0; fb<2; ++fb){
        bf[fb][0] = *(const h16x8*)(Bb + kbB[fb]);
        bf[fb][1] = *(const h16x8*)(Bb + (kbB[fb]^64));
      }
      if (q==0 && kt+1<16){ IB(kt+1,0); IA(kt+1,3); }
      if (q==1 && kt+1<16){ IB(kt+1,1); }
      if (q==2 && kt+2<16){ IA(kt+2,0); IA(kt+2,1); }
      if (q==3 && kt+2<16){ IA(kt+2,2); }
      __builtin_amdgcn_s_barrier();
      asm volatile("s_waitcnt lgkmcnt(0)" ::: "memory");
      __builtin_amdgcn_s_setprio(1);
      #pragma unroll
      for (int ks=0; ks<2; ++ks)
        #pragma unroll
        for (int f=0; f<4; ++f)
          #pragma unroll
          for (int fb=0; fb<2; ++fb)
            acc[4*q+f][fb] = __builtin_amdgcn_mfma_f32_16x16x32_f16(af[f][ks], bf[fb][ks], acc[4*q+f][fb], 0,0,0);
      __builtin_amdgcn_s_setprio(0);
      if (q==3){
        asm volatile("" ::: "memory");
        if (kt < 14)       asm volatile("s_waitcnt vmcnt(3)" ::: "memory");
        else if (kt == 14) asm volatile("s_waitcnt vmcnt(0)" ::: "memory");
      }
      __builtin_amdgcn_s_barrier();
    }
  }
  // epilogue: rows m0+16mf+4g+r; cols n0+32wc+16fb+l15; mat block-uniform
  const int mat = n0 >> 10;
  #pragma unroll
  for (int mf=0; mf<16; ++mf){
    const int grow0 = m0 + mf*16 + 4*g;
    #pragma unroll
    for (int fb=0; fb<2; ++fb){
      const int gcol = n0 + 32*wc + 16*fb + l15;
      const int hh = (gcol >> 6) & 15, d = gcol & 63;
      if (mat == 0){
        // Q: RoPE then TRANSPOSED store [bh][d][s], packed h16x4 (s-contiguous)
        const int pr = d >> 1;
        const int s0 = grow0 & 2047, b2 = grow0 >> 11;
        const int bh = b2*16 + hh;
        float rs4[4];
        #pragma unroll
        for (int r=0;r<4;++r){
          float2 t2 = tab[(s0+r)*32 + pr];
          float val = acc[mf][fb][r];
          float oth = __shfl_xor(val, 1);
          rs4[r] = fmaf(val, t2.x, (d & 1) ? oth*t2.y : -(oth*t2.y));
        }
        union { h16x4 v4; h16x2 h2[2]; } u;
        u.h2[0] = pkrtz(rs4[0], rs4[1]);
        u.h2[1] = pkrtz(rs4[2], rs4[3]);
        *(h16x4*)(outp + (size_t)bh*131072 + (size_t)d*2048 + s0) = u.v4;
      } else if (mat == 1){
        // K: RoPE then [64+bh][s][hd] scatter
        const int pr = d >> 1;
        #pragma unroll
        for (int r=0;r<4;++r){
          const int grow = grow0 + r;
          const int s = grow & 2047, b2 = grow >> 11;
          float2 t2 = tab[s*32 + pr];
          float val = acc[mf][fb][r];
          float oth = __shfl_xor(val, 1);
          float res = fmaf(val, t2.x, (d & 1) ? oth*t2.y : -(oth*t2.y));
          outp[((size_t)(64 + b2*16 + hh)*SB + s)*HDim + d] = (h16)res;
        }
      } else {
        // VT scatter: pos consecutive with r -> one h16x4 store
        const int s0 = grow0 & 2047, b2 = grow0 >> 11;
        const int bh = b2*16 + hh;
        const int pos0 = (s0 & ~63) + invp3(s0 & 63);
        union { h16x4 v4; h16x2 h2[2]; } u;
        u.h2[0] = pkrtz(acc[mf][fb][0], acc[mf][fb][1]);
        u.h2[1] = pkrtz(acc[mf][fb][2], acc[mf][fb][3]);
        *(h16x4*)(outp + (size_t)(128 + bh)*131072 + (size_t)d*2048 + pos0) = u.v4;
      }
    }
  }
}

// -------- MFMA GEMM, 128x128 tile, BK=64/barrier, 4 waves, 2-phase LDS dbuf --------
// (R17-proven; only MODE 1 is launched now.)
template<int MODE>
__global__ __launch_bounds__(256) void k_gemm(const h16* __restrict__ A,
                                              const h16* __restrict__ Bw,
                                              void* __restrict__ outp,
                                              const float2* __restrict__ tab){
  __shared__ __align__(16) char lds[65536];    // 2 x (As 16KB | Bs 16KB)
  const int t = threadIdx.x, lane = t & 63, wave = t >> 6;
  const int g = lane >> 4, l15 = lane & 15;
  const int lin = blockIdx.x;
  const int x = lin & 7, local = lin >> 3;
  const int m0p = local & 7, n0p = local >> 3;
  const int m0 = (x*8 + m0p)*128, n0 = n0p*128;
  const int wm = (wave >> 1)*64, wn = (wave & 1)*64;
  const int msk = (l15 & 7) << 4;
  const int kbA0 = (((wm + l15) << 7) + (g << 4)) ^ msk;
  const int kbA1 = kbA0 ^ 64;
  const int kbB0 = (((wn + l15) << 7) + (g << 4)) ^ msk;
  const int kbB1 = kbB0 ^ 64;
  const char* Asrc[4]; const char* Bsrc[4]; int od[4];
  #pragma unroll
  for (int i=0;i<4;++i){
    int o = t*16 + i*4096; od[i] = o;
    int lo = swz128(o);
    int row = lo >> 7, kb = lo & 127;
    Asrc[i] = (const char*)A  + (size_t)(m0+row)*2048 + kb;
    Bsrc[i] = (const char*)Bw + (size_t)(n0+row)*2048 + kb;
  }
  auto STAGE = [&](int s, char* d){
    const int kk = s*128;
    #pragma unroll
    for (int i=0;i<4;++i) gload16(Asrc[i] + kk, d + od[i]);
    #pragma unroll
    for (int i=0;i<4;++i) gload16(Bsrc[i] + kk, d + 16384 + od[i]);
  };
  f32x4 acc[4][4] = {};
  STAGE(0, lds);
  int cur = 0;
  for (int s = 0; s < 16; ++s){
    __syncthreads();
    if (s + 1 < 16) STAGE(s+1, lds + (cur^1)*32768);
    const char* As = lds + cur*32768;
    const char* Bs = As + 16384;
    #pragma unroll
    for (int ks=0; ks<2; ++ks){
      const int bA = ks ? kbA1 : kbA0;
      const int bB = ks ? kbB1 : kbB0;
      h16x8 af[4], bf[4];
      #pragma unroll
      for (int f=0; f<4; ++f){
        af[f] = *(const h16x8*)(As + bA + f*2048);
        bf[f] = *(const h16x8*)(Bs + bB + f*2048);
      }
      __builtin_amdgcn_s_setprio(1);
      #pragma unroll
      for (int fm=0; fm<4; ++fm)
        #pragma unroll
        for (int fn=0; fn<4; ++fn)
          acc[fm][fn] = __builtin_amdgcn_mfma_f32_16x16x32_f16(af[fm], bf[fn], acc[fm][fn], 0,0,0);
      __builtin_amdgcn_s_setprio(0);
    }
    cur ^= 1;
  }
  #pragma unroll
  for (int fm=0; fm<4; ++fm){
    int grow0 = m0 + wm + fm*16 + 4*g;
    #pragma unroll
    for (int fn=0; fn<4; ++fn){
      int gcol = n0 + wn + fn*16 + l15;
      #pragma unroll
      for (int r=0;r<4;++r){
        int grow = grow0 + r;
        ((float*)outp)[(size_t)grow*DM + gcol] = acc[fm][fn][r];
      }
    }
  }
}

// ------- causal flash attention: 8 waves x 16q, paired-static, KVBLK=128/barrier (R15) -------
__global__ __launch_bounds__(512, 4) void k_attn(const h16* __restrict__ Qh,
                                                 const h16* __restrict__ Kh,
                                                 const h16* __restrict__ VTh,
                                                 h16* __restrict__ Ctx){
  __shared__ __align__(16) char Kl[2][16384];  // 2 sub-tiles x [64 k][64 hd], swz128
  __shared__ __align__(16) char Vl[2][16384];  // 2 sub-tiles x [64 hd][64 pos], swz128
  const int t = threadIdx.x, lane = t & 63, wave = t >> 6;
  const int g = lane >> 4, l15 = lane & 15;
  const int msk = (l15 & 7) << 4;
  const int kb0 = ((l15 << 7) + (g << 4)) ^ msk;
  const int kb1 = kb0 ^ 64;
  const int o0 = t*16;
  const int lo0 = swz128(o0);
  const int vof0 = ((lo0 >> 7) << 12) + (lo0 & 127);
  h16x8 ones;
  #pragma unroll
  for (int i=0;i<8;++i) ones[i] = (h16)1.0f;

  const int lin = blockIdx.x;
  const int sz = (lin & 7)*64 + (lin >> 3);
  const int bh = sz >> 3, pr = sz & 7;
  const char* Qb = (const char*)Qh + (size_t)bh*262144;   // [64 hd][2048 s]
  const char* Kb = (const char*)Kh + (size_t)bh*262144;   // [2048 s][64 hd]
  const char* Vb = (const char*)VTh + (size_t)bh*262144;  // [64 hd][2048 pos]
  const int b = bh >> 4, h = bh & 15;

  #pragma unroll
  for (int seg=0; seg<2; ++seg){
    const int J = seg ? pr : (15 - pr);    // heavy tile first
    const int qw = (J << 7) + wave*16;
    union { h16x8 v; h16 e[8]; } uq0, uq1;
    const char* Qcol = Qb + (size_t)(qw + l15)*2;
    #pragma unroll
    for (int j=0;j<8;++j){
      uq0.e[j] = *(const h16*)(Qcol + (size_t)(8*g + j)*4096);
      uq1.e[j] = *(const h16*)(Qcol + (size_t)(32 + 8*g + j)*4096);
    }
    const h16x8 qf0 = uq0.v, qf1 = uq1.v;
    f32x4 acc[4] = {};
    float lrow = 0.f;
    const int nkt = J + 1;                 // 128-key steps
    const char* kS = Kb + lo0;
    const char* vS = Vb + vof0;
    __syncthreads();
    gload16(kS,        &Kl[0][o0]);
    gload16(kS + 8192, &Kl[0][8192 + o0]);
    gload16(vS,        &Vl[0][o0]);
    gload16(vS + 128,  &Vl[0][8192 + o0]);
    int buf = 0;
    for (int kt=0; kt<nkt; ++kt){
      __syncthreads();
      if (kt+1 < nkt){
        const size_t kB = (size_t)(kt+1)*16384, vB = (size_t)(kt+1)*256;
        gload16(kS + kB,        &Kl[buf^1][o0]);
        gload16(kS + kB + 8192, &Kl[buf^1][8192 + o0]);
        gload16(vS + vB,        &Vl[buf^1][o0]);
        gload16(vS + vB + 128,  &Vl[buf^1][8192 + o0]);
      }
      #pragma unroll
      for (int n=0; n<2; ++n){
        const int k0 = kt*128 + 64*n;
        if (k0 <= qw + 15){
          const char* Kt = &Kl[buf][n*8192];
          const char* Vt = &Vl[buf][n*8192];
          f32x4 sfr[4] = {};
          {
            h16x8 kf0[4];
            #pragma unroll
            for (int kf=0;kf<4;++kf) kf0[kf] = *(const h16x8*)(Kt + kb0 + 2048*kf);
            __builtin_amdgcn_s_setprio(1);
            #pragma unroll
            for (int kf=0;kf<4;++kf)
              sfr[kf] = __builtin_amdgcn_mfma_f32_16x16x32_f16(kf0[kf], qf0, sfr[kf], 0,0,0);
            __builtin_amdgcn_s_setprio(0);
            h16x8 kf1[4];
            #pragma unroll
            for (int kf=0;kf<4;++kf) kf1[kf] = *(const h16x8*)(Kt + kb1 + 2048*kf);
            __builtin_amdgcn_s_setprio(1);
            #pragma unroll
            for (int kf=0;kf<4;++kf)
              sfr[kf] = __builtin_amdgcn_mfma_f32_16x16x32_f16(kf1[kf], qf1, sfr[kf], 0,0,0);
            __builtin_amdgcn_s_setprio(0);
          }
          if (k0 + 63 > qw){
            const int qg = qw + l15;
            #pragma unroll
            for (int kf=0;kf<4;++kf){
              const int kb = k0 + 16*kf + 4*g;
              #pragma unroll
              for (int r=0;r<4;++r)
                if (kb + r > qg) sfr[kf][r] = -1e30f;
            }
          }
          float e[4][4];
          #pragma unroll
          for (int kf=0;kf<4;++kf)
            #pragma unroll
            for (int r=0;r<4;++r)
              e[kf][r] = exp2f(sfr[kf][r]);
          h16x8 pa[2];
          #pragma unroll
          for (int s=0;s<2;++s){
            union { h16x8 v8; h16x2 h2[4]; } u;
            u.h2[0] = pkrtz(e[2*s][0],   e[2*s][1]);
            u.h2[1] = pkrtz(e[2*s][2],   e[2*s][3]);
            u.h2[2] = pkrtz(e[2*s+1][0], e[2*s+1][1]);
            u.h2[3] = pkrtz(e[2*s+1][2], e[2*s+1][3]);
            pa[s] = u.v8;
          }
          f32x4 zs = {};
          zs = __builtin_amdgcn_mfma_f32_16x16x32_f16(ones, pa[0], zs, 0,0,0);
          zs = __builtin_amdgcn_mfma_f32_16x16x32_f16(ones, pa[1], zs, 0,0,0);
          #pragma unroll
          for (int s=0;s<2;++s){
            h16x8 vb2[4];
            const int base = s ? kb1 : kb0;
            #pragma unroll
            for (int v=0;v<4;++v) vb2[v] = *(const h16x8*)(Vt + base + 2048*v);
            __builtin_amdgcn_s_setprio(1);
            #pragma unroll
            for (int v=0;v<4;++v)
              acc[v] = __builtin_amdgcn_mfma_f32_16x16x32_f16(vb2[v], pa[s], acc[v], 0,0,0);
            __builtin_amdgcn_s_setprio(0);
          }
          lrow += zs[0];
        }
      }
      buf ^= 1;
    }
    const float rinv = 1.0f / lrow;
    h16* basep = Ctx + ((size_t)(b*SB + qw + l15))*DM + h*64 + (g<<2);
    #pragma unroll
    for (int v=0;v<4;++v){
      union { h16x4 v4; h16x2 h2[2]; } u;
      u.h2[0] = pkrtz(acc[v][0]*rinv, acc[v][1]*rinv);
      u.h2[1] = pkrtz(acc[v][2]*rinv, acc[v][3]*rinv);
      *(h16x4*)(basep + 16*v) = u.v4;
    }
  }
}

extern "C" void kernel_launch(void* const* d_in, const int* in_sizes, int n_in,
                              void* d_out, int out_size, void* d_ws, size_t ws_size,
                              hipStream_t stream) {
  const float* x  = (const float*)d_in[0];
  const int*  tok = (const int*)d_in[1];
  const float* wq = (const float*)d_in[2];
  const float* wk = (const float*)d_in[3];
  const float* wv = (const float*)d_in[4];
  const float* wo = (const float*)d_in[5];
  float* out = (float*)d_out;
  char* ws = (char*)d_ws;
  // ws layout: Xb 16MB (reused as Ctx) | WT 8MB | QKV 48MB (Q^T|K|VT)
  // RoPE table (512KB) in d_out's head (scratch until k_gemm<1> overwrites).
  if (ws_size < (size_t)75497472) return;
  h16* Xb  = (h16*)ws;
  h16* WT  = (h16*)(ws + (16u<<20));
  h16* QKV = (h16*)(ws + (24u<<20));
  float2* tab = (float2*)d_out;

  k_prep<<<dim3(6400), dim3(256), 0, stream>>>(x, Xb, wq, wk, wv, wo, WT, tok, tab);
  k_gemm8<<<dim3(384), dim3(512), 0, stream>>>(Xb, WT, QKV, tab);
  k_attn<<<dim3(512), dim3(512), 0, stream>>>(QKV,
                                              QKV + (size_t)64*SB*HDim,
                                              QKV + (size_t)128*SB*HDim,
                                              Xb);
  k_gemm<1><<<dim3(512), dim3(256), 0, stream>>>(Xb, WT + (size_t)3*DM*DM, (void*)out, nullptr);
}

// Round 21
// 166.940 us; speedup vs baseline: 1.0694x; 1.0694x over previous
//
#include <hip/hip_runtime.h>

// Problem constants (B=4, S=2048, D=1024, H=16, HD=64, theta=10000)
#define SB 2048
#define DM 1024
#define NH 16
#define HDim 64
#define NB 4
#define MROWS (NB*SB)   // 8192

typedef _Float16 h16;
typedef __attribute__((ext_vector_type(8))) _Float16 h16x8;
typedef __attribute__((ext_vector_type(4))) _Float16 h16x4;
typedef __attribute__((ext_vector_type(2))) _Float16 h16x2;
typedef __attribute__((ext_vector_type(2))) __fp16 fp16x2;
typedef __attribute__((ext_vector_type(4))) float f32x4;

typedef const __attribute__((address_space(1))) void* as1cp;
typedef __attribute__((address_space(3))) void* as3p;

__device__ __forceinline__ void gload16(const void* g, void* l){
  __builtin_amdgcn_global_load_lds((as1cp)g, (as3p)l, 16, 0, 0);
}
__device__ __forceinline__ int swz128(int a){ return a ^ (((a>>7)&7)<<4); }
// V k-permutation (pos->k) inverse, used when writing VT (see round-1 notes)
__device__ __forceinline__ int invp3(int k){ return (k&32) | ((k&16)>>2) | ((k&12)<<1) | (k&3); }
__device__ __forceinline__ h16x2 pkrtz(float a, float b){
  fp16x2 r = __builtin_amdgcn_cvt_pkrtz(a,b);
  return __builtin_bit_cast(h16x2, r);
}

#define C1 0.18033688f   // 0.125 * log2(e); folded into wq at cvt_w

// ------- merged prep: [0,2048) cvt_x | [2048,6144) cvt_w(+C1 on wq) | [6144,6400) RoPE tab -------
__global__ void k_prep(const float* __restrict__ x, h16* __restrict__ xb,
                       const float* __restrict__ wq, const float* __restrict__ wk,
                       const float* __restrict__ wv, const float* __restrict__ wo,
                       h16* __restrict__ WT,
                       const int* __restrict__ tok, float2* __restrict__ tab){
  __shared__ h16 tile[32][33];
  const int blk = blockIdx.x;
  if (blk < 2048){
    const int n4 = MROWS*DM/4;
    for (int i = blk*blockDim.x + threadIdx.x; i < n4; i += 2048*blockDim.x){
      float4 v = ((const float4*)x)[i];
      h16x4 h; h[0]=(h16)v.x; h[1]=(h16)v.y; h[2]=(h16)v.z; h[3]=(h16)v.w;
      ((h16x4*)xb)[i] = h;
    }
  } else if (blk < 6144){
    const int local = blk - 2048;
    const int z = local >> 10, rem = local & 1023;
    const float* W = (z==0)?wq:(z==1)?wk:(z==2)?wv:wo;
    const float sc = (z==0) ? C1 : 1.0f;
    int tx = threadIdx.x & 31, ty = threadIdx.x >> 5;
    int n0 = (rem & 31)*32, k0 = (rem >> 5)*32;
    #pragma unroll
    for (int j=0;j<4;++j)
      tile[ty*4+j][tx] = (h16)(W[(size_t)(k0+ty*4+j)*DM + n0 + tx] * sc);
    __syncthreads();
    #pragma unroll
    for (int j=0;j<4;++j)
      WT[((size_t)z*DM + n0 + ty*4 + j)*DM + k0 + tx] = tile[tx][ty*4+j];
  } else {
    int i = (blk - 6144)*blockDim.x + threadIdx.x;   // 65536 entries
    int pr = i & 31, s = i >> 5;
    float inv = exp2f(-0.41524101f * (float)pr);
    float ang = (float)tok[s] * inv;
    float sn, cs; __sincosf(ang, &sn, &cs);
    tab[i] = make_float2(cs, sn);
  }
}

// -------- MFMA GEMM, 128x128 tile, BK=64/barrier, 4 waves, 2-phase LDS dbuf --------
// XCD m-stripe partition, M-FASTEST within stripe: concurrent blocks on an XCD
// span all 8 m-panels (2MB A) x ~6 n-panels (1.5MB B) = 3.5MB < 4MB L2 -> both
// operands L2-resident. Panels [128 rows][64 k], 128B rows, swz128 XOR layout
// (0 bank conflicts). 32 MFMA between barriers (R16's lever).
// MODE 0: C=[8192]x[3072]; Q RoPE'd -> TRANSPOSED [bh][hd][s]; K RoPE'd ->
//         [bh][s][hd]; V -> permuted VT [bh][hd][pos].
// MODE 1: C=[8192]x[1024] -> fp32 linear to d_out
template<int MODE>
__global__ __launch_bounds__(256) void k_gemm(const h16* __restrict__ A,
                                              const h16* __restrict__ Bw,
                                              void* __restrict__ outp,
                                              const float2* __restrict__ tab){
  __shared__ __align__(16) char lds[65536];    // 2 x (As 16KB | Bs 16KB)
  const int t = threadIdx.x, lane = t & 63, wave = t >> 6;
  const int g = lane >> 4, l15 = lane & 15;
  // XCD m-stripe block map, m-fastest (grid: MODE0=1536, MODE1=512; both %8==0)
  const int lin = blockIdx.x;
  const int x = lin & 7, local = lin >> 3;
  const int m0p = local & 7, n0p = local >> 3;
  const int m0 = (x*8 + m0p)*128, n0 = n0p*128;
  const int wm = (wave >> 1)*64, wn = (wave & 1)*64;
  // lane-constant LDS read bases (both ks variants hoisted)
  const int msk = (l15 & 7) << 4;
  const int kbA0 = (((wm + l15) << 7) + (g << 4)) ^ msk;
  const int kbA1 = kbA0 ^ 64;
  const int kbB0 = (((wn + l15) << 7) + (g << 4)) ^ msk;
  const int kbB1 = kbB0 ^ 64;
  // thread-constant staging sources (pre-swizzled): 4 issues x 4KB per operand
  const char* Asrc[4]; const char* Bsrc[4]; int od[4];
  #pragma unroll
  for (int i=0;i<4;++i){
    int o = t*16 + i*4096; od[i] = o;
    int lo = swz128(o);
    int row = lo >> 7, kb = lo & 127;
    Asrc[i] = (const char*)A  + (size_t)(m0+row)*2048 + kb;
    Bsrc[i] = (const char*)Bw + (size_t)(n0+row)*2048 + kb;
  }
  auto STAGE = [&](int s, char* d){
    const int kk = s*128;                  // 64 k = 128 bytes along K
    #pragma unroll
    for (int i=0;i<4;++i) gload16(Asrc[i] + kk, d + od[i]);
    #pragma unroll
    for (int i=0;i<4;++i) gload16(Bsrc[i] + kk, d + 16384 + od[i]);
  };
  f32x4 acc[4][4] = {};
  STAGE(0, lds);                           // prologue: step 0 -> buf 0
  int cur = 0;
  for (int s = 0; s < 16; ++s){
    __syncthreads();                       // vmcnt(0): buf[cur] staged; prev reads done
    if (s + 1 < 16) STAGE(s+1, lds + (cur^1)*32768);
    const char* As = lds + cur*32768;
    const char* Bs = As + 16384;
    #pragma unroll
    for (int ks=0; ks<2; ++ks){
      const int bA = ks ? kbA1 : kbA0;
      const int bB = ks ? kbB1 : kbB0;
      h16x8 af[4], bf[4];
      #pragma unroll
      for (int f=0; f<4; ++f){
        af[f] = *(const h16x8*)(As + bA + f*2048);
        bf[f] = *(const h16x8*)(Bs + bB + f*2048);
      }
      __builtin_amdgcn_s_setprio(1);
      #pragma unroll
      for (int fm=0; fm<4; ++fm)
        #pragma unroll
        for (int fn=0; fn<4; ++fn)
          acc[fm][fn] = __builtin_amdgcn_mfma_f32_16x16x32_f16(af[fm], bf[fn], acc[fm][fn], 0,0,0);
      __builtin_amdgcn_s_setprio(0);
    }
    cur ^= 1;
  }
  // epilogue; D layout: col = lane&15, row = 4*(lane>>4)+r
  #pragma unroll
  for (int fm=0; fm<4; ++fm){
    int grow0 = m0 + wm + fm*16 + 4*g;
    #pragma unroll
    for (int fn=0; fn<4; ++fn){
      int gcol = n0 + wn + fn*16 + l15;
      if (MODE == 0){
        int mat = gcol >> 10;                 // wave-uniform per fn
        int hh = (gcol >> 6) & 15, d = gcol & 63;
        if (mat == 0){
          // Q: RoPE then TRANSPOSED store [bh][d][s], packed h16x4 (s-contiguous)
          const int pr = d >> 1;
          int s0 = grow0 & 2047, b2 = grow0 >> 11;
          int bh = b2*16 + hh;
          float rs4[4];
          #pragma unroll
          for (int r=0;r<4;++r){
            float2 t2 = tab[(s0+r)*32 + pr];
            float val = acc[fm][fn][r];
            float oth = __shfl_xor(val, 1);
            rs4[r] = fmaf(val, t2.x, (d & 1) ? oth*t2.y : -(oth*t2.y));
          }
          union { h16x4 v4; h16x2 h2[2]; } u;
          u.h2[0] = pkrtz(rs4[0], rs4[1]);
          u.h2[1] = pkrtz(rs4[2], rs4[3]);
          *(h16x4*)((h16*)outp + (size_t)bh*131072 + (size_t)d*2048 + s0) = u.v4;
        } else if (mat == 1){
          // K: RoPE then [64+bh][s][hd] scatter (attn stages K rows by s)
          const int pr = d >> 1;
          #pragma unroll
          for (int r=0;r<4;++r){
            int grow = grow0 + r;
            int s = grow & 2047, b2 = grow >> 11;
            float2 t2 = tab[s*32 + pr];
            float val = acc[fm][fn][r];
            float oth = __shfl_xor(val, 1);
            float res = fmaf(val, t2.x, (d & 1) ? oth*t2.y : -(oth*t2.y));
            ((h16*)outp)[((size_t)(64 + b2*16 + hh)*SB + s)*HDim + d] = (h16)res;
          }
        } else {
          // VT scatter: pos runs consecutively with r -> one h16x4 store
          int s0 = grow0 & 2047, b2 = grow0 >> 11;
          int bh = b2*16 + hh;
          int pos0 = (s0 & ~63) + invp3(s0 & 63);
          union { h16x4 v4; h16x2 h2[2]; } u;
          u.h2[0] = pkrtz(acc[fm][fn][0], acc[fm][fn][1]);
          u.h2[1] = pkrtz(acc[fm][fn][2], acc[fm][fn][3]);
          *(h16x4*)((h16*)outp + (size_t)(128 + bh)*131072 + (size_t)d*2048 + pos0) = u.v4;
        }
      } else {
        #pragma unroll
        for (int r=0;r<4;++r){
          int grow = grow0 + r;
          ((float*)outp)[(size_t)grow*DM + gcol] = acc[fm][fn][r];
        }
      }
    }
  }
}

// ------- causal flash attention: 8 waves x 16q, paired-static, KVBLK=128/barrier (R15) -------
// 512 blocks x 512 thr. Block = (bh, pair p): q-tiles J=15-p then J=p -> 17
// stage-steps/block (constant). Each step stages TWO 64-key sub-tiles (stored as
// independent 8KB sub-tiles). LDS 64KB -> 2 blocks/CU. QK^T: mfma(K,Q) -> lane
// owns q-row. P = exp2(s) directly (Q pre-scaled by C1). Row-sum via mfma(ones,P).
// PV: mfma(VT,P), VT pre-permuted (invp3). Q gathered from transposed [bh][hd][s].
__global__ __launch_bounds__(512, 4) void k_attn(const h16* __restrict__ Qh,
                                                 const h16* __restrict__ Kh,
                                                 const h16* __restrict__ VTh,
                                                 h16* __restrict__ Ctx){
  __shared__ __align__(16) char Kl[2][16384];  // 2 sub-tiles x [64 k][64 hd], swz128
  __shared__ __align__(16) char Vl[2][16384];  // 2 sub-tiles x [64 hd][64 pos], swz128
  const int t = threadIdx.x, lane = t & 63, wave = t >> 6;
  const int g = lane >> 4, l15 = lane & 15;
  // lane-constant LDS read bases (see R4 notes): addr = kb_hs + 2048*u
  const int msk = (l15 & 7) << 4;
  const int kb0 = ((l15 << 7) + (g << 4)) ^ msk;
  const int kb1 = kb0 ^ 64;
  // thread-constant staging offsets (512 threads cover one 8KB sub-tile at 16B each)
  const int o0 = t*16;
  const int lo0 = swz128(o0);
  const int vof0 = ((lo0 >> 7) << 12) + (lo0 & 127);
  h16x8 ones;
  #pragma unroll
  for (int i=0;i<8;++i) ones[i] = (h16)1.0f;

  // static XCD-clustered item map: bh's 8 pair-blocks share blockIdx%8 -> one XCD
  const int lin = blockIdx.x;
  const int sz = (lin & 7)*64 + (lin >> 3);
  const int bh = sz >> 3, pr = sz & 7;
  const char* Qb = (const char*)Qh + (size_t)bh*262144;   // [64 hd][2048 s]
  const char* Kb = (const char*)Kh + (size_t)bh*262144;   // [2048 s][64 hd]
  const char* Vb = (const char*)VTh + (size_t)bh*262144;  // [64 hd][2048 pos]
  const int b = bh >> 4, h = bh & 15;

  #pragma unroll
  for (int seg=0; seg<2; ++seg){
    const int J = seg ? pr : (15 - pr);    // heavy tile first
    const int qw = (J << 7) + wave*16;     // wave owns q in [qw, qw+16)
    // gather Q fragments from transposed layout: q row = qw+l15, hd = 8g+j (+32)
    union { h16x8 v; h16 e[8]; } uq0, uq1;
    const char* Qcol = Qb + (size_t)(qw + l15)*2;
    #pragma unroll
    for (int j=0;j<8;++j){
      uq0.e[j] = *(const h16*)(Qcol + (size_t)(8*g + j)*4096);
      uq1.e[j] = *(const h16*)(Qcol + (size_t)(32 + 8*g + j)*4096);
    }
    const h16x8 qf0 = uq0.v, qf1 = uq1.v;
    f32x4 acc[4] = {};
    float lrow = 0.f;
    const int nkt = J + 1;                 // 128-key steps
    const char* kS = Kb + lo0;
    const char* vS = Vb + vof0;
    __syncthreads();                       // prior seg's LDS reads done
    gload16(kS,        &Kl[0][o0]);
    gload16(kS + 8192, &Kl[0][8192 + o0]);
    gload16(vS,        &Vl[0][o0]);
    gload16(vS + 128,  &Vl[0][8192 + o0]);
    int buf = 0;
    for (int kt=0; kt<nkt; ++kt){
      __syncthreads();                     // drains vmcnt, publishes buf
      if (kt+1 < nkt){
        const size_t kB = (size_t)(kt+1)*16384, vB = (size_t)(kt+1)*256;
        gload16(kS + kB,        &Kl[buf^1][o0]);
        gload16(kS + kB + 8192, &Kl[buf^1][8192 + o0]);
        gload16(vS + vB,        &Vl[buf^1][o0]);
        gload16(vS + vB + 128,  &Vl[buf^1][8192 + o0]);
      }
      #pragma unroll
      for (int n=0; n<2; ++n){
        const int k0 = kt*128 + 64*n;
        if (k0 <= qw + 15){                // wave-uniform causal skip (per sub-tile)
          const char* Kt = &Kl[buf][n*8192];
          const char* Vt = &Vl[buf][n*8192];
          f32x4 sfr[4] = {};
          {
            h16x8 kf0[4];
            #pragma unroll
            for (int kf=0;kf<4;++kf) kf0[kf] = *(const h16x8*)(Kt + kb0 + 2048*kf);
            __builtin_amdgcn_s_setprio(1);
            #pragma unroll
            for (int kf=0;kf<4;++kf)
              sfr[kf] = __builtin_amdgcn_mfma_f32_16x16x32_f16(kf0[kf], qf0, sfr[kf], 0,0,0);
            __builtin_amdgcn_s_setprio(0);
            h16x8 kf1[4];
            #pragma unroll
            for (int kf=0;kf<4;++kf) kf1[kf] = *(const h16x8*)(Kt + kb1 + 2048*kf);
            __builtin_amdgcn_s_setprio(1);
            #pragma unroll
            for (int kf=0;kf<4;++kf)
              sfr[kf] = __builtin_amdgcn_mfma_f32_16x16x32_f16(kf1[kf], qf1, sfr[kf], 0,0,0);
            __builtin_amdgcn_s_setprio(0);
          }
          if (k0 + 63 > qw){               // diagonal sub-tile: causal mask
            const int qg = qw + l15;
            #pragma unroll
            for (int kf=0;kf<4;++kf){
              const int kb = k0 + 16*kf + 4*g;
              #pragma unroll
              for (int r=0;r<4;++r)
                if (kb + r > qg) sfr[kf][r] = -1e30f;
            }
          }
          float e[4][4];
          #pragma unroll
          for (int kf=0;kf<4;++kf)
            #pragma unroll
            for (int r=0;r<4;++r)
              e[kf][r] = exp2f(sfr[kf][r]);
          h16x8 pa[2];
          #pragma unroll
          for (int s=0;s<2;++s){
            union { h16x8 v8; h16x2 h2[4]; } u;
            u.h2[0] = pkrtz(e[2*s][0],   e[2*s][1]);
            u.h2[1] = pkrtz(e[2*s][2],   e[2*s][3]);
            u.h2[2] = pkrtz(e[2*s+1][0], e[2*s+1][1]);
            u.h2[3] = pkrtz(e[2*s+1][2], e[2*s+1][3]);
            pa[s] = u.v8;
          }
          f32x4 zs = {};
          zs = __builtin_amdgcn_mfma_f32_16x16x32_f16(ones, pa[0], zs, 0,0,0);
          zs = __builtin_amdgcn_mfma_f32_16x16x32_f16(ones, pa[1], zs, 0,0,0);
          #pragma unroll
          for (int s=0;s<2;++s){
            h16x8 vb2[4];
            const int base = s ? kb1 : kb0;
            #pragma unroll
            for (int v=0;v<4;++v) vb2[v] = *(const h16x8*)(Vt + base + 2048*v);
            __builtin_amdgcn_s_setprio(1);
            #pragma unroll
            for (int v=0;v<4;++v)
              acc[v] = __builtin_amdgcn_mfma_f32_16x16x32_f16(vb2[v], pa[s], acc[v], 0,0,0);
            __builtin_amdgcn_s_setprio(0);
          }
          lrow += zs[0];
        }
      }
      buf ^= 1;
    }
    // epilogue: lane owns row q = qw+l15; cols hd = 16v+4g+r -> packed 8B stores
    const float rinv = 1.0f / lrow;
    h16* basep = Ctx + ((size_t)(b*SB + qw + l15))*DM + h*64 + (g<<2);
    #pragma unroll
    for (int v=0;v<4;++v){
      union { h16x4 v4; h16x2 h2[2]; } u;
      u.h2[0] = pkrtz(acc[v][0]*rinv, acc[v][1]*rinv);
      u.h2[1] = pkrtz(acc[v][2]*rinv, acc[v][3]*rinv);
      *(h16x4*)(basep + 16*v) = u.v4;
    }
  }
}

extern "C" void kernel_launch(void* const* d_in, const int* in_sizes, int n_in,
                              void* d_out, int out_size, void* d_ws, size_t ws_size,
                              hipStream_t stream) {
  const float* x  = (const float*)d_in[0];
  const int*  tok = (const int*)d_in[1];
  const float* wq = (const float*)d_in[2];
  const float* wk = (const float*)d_in[3];
  const float* wv = (const float*)d_in[4];
  const float* wo = (const float*)d_in[5];
  float* out = (float*)d_out;
  char* ws = (char*)d_ws;
  // ws layout: Xb 16MB (reused as Ctx) | WT 8MB | QKV 48MB (Q^T|K|VT)
  // RoPE table (512KB) lives in d_out's head: free scratch until k_gemm<1>
  // fully overwrites d_out at the end.
  if (ws_size < (size_t)75497472) return;
  h16* Xb  = (h16*)ws;
  h16* WT  = (h16*)(ws + (16u<<20));
  h16* QKV = (h16*)(ws + (24u<<20));
  float2* tab = (float2*)d_out;

  k_prep<<<dim3(6400), dim3(256), 0, stream>>>(x, Xb, wq, wk, wv, wo, WT, tok, tab);
  k_gemm<0><<<dim3(1536), dim3(256), 0, stream>>>(Xb, WT, (void*)QKV, tab);
  k_attn<<<dim3(512), dim3(512), 0, stream>>>(QKV,
                                              QKV + (size_t)64*SB*HDim,
                                              QKV + (size_t)128*SB*HDim,
                                              Xb);
  k_gemm<1><<<dim3(512), dim3(256), 0, stream>>>(Xb, WT + (size_t)3*DM*DM, (void*)out, nullptr);
}